// Round 9
// baseline (80.854 us; speedup 1.0000x reference)
//
#include <hip/hip_runtime.h>

#define NBINS 128

// Fixed problem shape: n = 8192 rows, d = 512 cols.
// Grid: 512 blocks = (cg in [0,8)) x (rg in [0,64)); bid = rg*8 + cg.
// Block (cg,rg) owns rows [rg*128, rg*128+128) x cols [cg*64, cg*64+64).
//
// ws layout (bytes) — every byte the finalizer reads is plain-stored exactly
// once by some block (no zero-init, no global atomics except the ticket):
//   [0,      131072)  float uslab[64][512]
//   [131072, 262144)  float vslab[64][512]
//   [262144, 264192)  float scalT[512]
//   [264192, 266240)  float scalP[512]
//   [266240, 268288)  float scalQ[512]
//   [268288, 268544)  float scalW[64]
//   [268544, 268548)  uint  ticket   (harness poison 0xAAAAAAAA is the known init)

__global__ __launch_bounds__(256) void fused(const float* __restrict__ x,
                                             const int* __restrict__ tgt,
                                             float* __restrict__ uslab,
                                             float* __restrict__ vslab,
                                             float* __restrict__ scalT,
                                             float* __restrict__ scalP,
                                             float* __restrict__ scalQ,
                                             float* __restrict__ scalW,
                                             unsigned int* __restrict__ ticket,
                                             int n, int d,
                                             float* __restrict__ out) {
    const int tid  = threadIdx.x;
    const int bid  = blockIdx.x;
    const int cg   = bid & 7;     // column group (64 cols)
    const int rg   = bid >> 3;    // row group (128 rows)
    const int wave = tid >> 6, lane = tid & 63;

    __shared__ float xbuf[128 * 64];   // 32 KB tile
    __shared__ int   hw[4][NBINS];     // wave-private histograms
    __shared__ float crow[128];        // class counts for the block's rows
    __shared__ float ured[256 * 4];    // per-thread float4 u partials
    __shared__ float vred[256 * 4];
    __shared__ float redS[3][4];
    __shared__ unsigned int lastflag;

    // ---- (1) stage the 32 KB tile: 8 async 16B direct-to-LDS copies/thread ----
    const float* xb = x + (size_t)(rg * 128) * 512 + cg * 64;
    #pragma unroll
    for (int k = 0; k < 8; ++k) {
        const int e16   = (k * 4 + wave) * 64 + lane;
        const int row   = e16 >> 4;
        const int chunk = e16 & 15;
        const float* gptr = xb + (size_t)row * 512 + chunk * 4;
        float* lbase = &xbuf[(k * 4 + wave) * 256];   // wave-uniform; lane at +lane*16B
        __builtin_amdgcn_global_load_lds(
            (const __attribute__((address_space(1))) void*)gptr,
            (__attribute__((address_space(3))) void*)lbase, 16, 0, 0);
    }

    // ---- (2) targets: 8 int4/thread (all 8192), in flight with the staging ----
    int4 tv[8];
    const int4* t4 = (const int4*)tgt;
    #pragma unroll
    for (int k = 0; k < 8; ++k) tv[k] = t4[k * 256 + tid];

    const int mylab = (tid < 128) ? tgt[rg * 128 + tid] : 0;

    // ---- (3) wave-private LDS histogram ----
    hw[wave][lane] = 0;
    hw[wave][lane + 64] = 0;
    #pragma unroll
    for (int k = 0; k < 8; ++k) {
        atomicAdd(&hw[wave][tv[k].x & (NBINS - 1)], 1);
        atomicAdd(&hw[wave][tv[k].y & (NBINS - 1)], 1);
        atomicAdd(&hw[wave][tv[k].z & (NBINS - 1)], 1);
        atomicAdd(&hw[wave][tv[k].w & (NBINS - 1)], 1);
    }
    __syncthreads();   // drains staging vmcnt + all hist atomics

    if (tid < 128) {
        const int b = mylab & (NBINS - 1);
        crow[tid] = (float)(hw[0][b] + hw[1][b] + hw[2][b] + hw[3][b]);
    }
    __syncthreads();

    // ---- (4) accumulate: thread t -> col-quad q = t&15, rows g+16k, g = t>>4 ----
    const int q = tid & 15, g = tid >> 4;
    float t_acc = 0.f, p_acc = 0.f, q_acc = 0.f;
    float4 ua = make_float4(0.f, 0.f, 0.f, 0.f);
    float4 va = make_float4(0.f, 0.f, 0.f, 0.f);
    #pragma unroll
    for (int k = 0; k < 8; ++k) {
        const int r = g + 16 * k;
        const float c = crow[r];
        const float4 v = ((const float4*)xbuf)[r * 16 + q];
        const float sq = v.x*v.x + v.y*v.y + v.z*v.z + v.w*v.w;
        const float sm = v.x + v.y + v.z + v.w;
        t_acc += sq;
        p_acc += c * sq;
        q_acc += c * sm;
        ua.x += v.x;     ua.y += v.y;     ua.z += v.z;     ua.w += v.w;
        va.x += c * v.x; va.y += c * v.y; va.z += c * v.z; va.w += c * v.w;
    }

    ((float4*)ured)[tid] = ua;
    ((float4*)vred)[tid] = va;

    for (int off = 32; off > 0; off >>= 1) {
        t_acc += __shfl_down(t_acc, off);
        p_acc += __shfl_down(p_acc, off);
        q_acc += __shfl_down(q_acc, off);
    }
    if (lane == 0) { redS[0][wave] = t_acc; redS[1][wave] = p_acc; redS[2][wave] = q_acc; }
    __syncthreads();   // covers ured/vred and redS

    // ---- (5) column reduction + disjoint slab stores (no atomics) ----
    if (tid < 64) {
        const int cq = tid >> 2, ce = tid & 3;
        float su = 0.f, sv = 0.f;
        #pragma unroll
        for (int gg = 0; gg < 16; ++gg) {
            su += ured[(gg * 16 + cq) * 4 + ce];
            sv += vred[(gg * 16 + cq) * 4 + ce];
        }
        uslab[rg * 512 + cg * 64 + tid] = su;
        vslab[rg * 512 + cg * 64 + tid] = sv;
    }

    if (wave == 1) {
        float w = crow[lane] + crow[lane + 64];
        for (int off = 32; off > 0; off >>= 1) w += __shfl_down(w, off);
        if (lane == 0 && cg == 0) scalW[rg] = w;
    }

    // ---- (6) ticket: release all stores, last block finalizes ----
    __syncthreads();   // all waves' stores issued & vmcnt-drained at barrier
    if (tid == 0) {
        scalT[bid] = redS[0][0] + redS[0][1] + redS[0][2] + redS[0][3];
        scalP[bid] = redS[1][0] + redS[1][1] + redS[1][2] + redS[1][3];
        scalQ[bid] = redS[2][0] + redS[2][1] + redS[2][2] + redS[2][3];
        // agent-scope ACQ_REL: release = wbL2 (pushes all this XCD's stores to
        // device-coherent point); acquire = invL2 for the winner's fresh reads.
        unsigned int old = __hip_atomic_fetch_add(ticket, 1u, __ATOMIC_ACQ_REL,
                                                  __HIP_MEMORY_SCOPE_AGENT);
        lastflag = (old == 0xAAAAAAAAu + 511u) || (old == 511u);
    }
    __syncthreads();
    if (!lastflag) return;

    // ---- (7) finalize (last block only): reduce slabs + scalars, closed form ----
    float2 su = make_float2(0.f, 0.f), sv = make_float2(0.f, 0.f);
    const float2* u2 = (const float2*)uslab;
    const float2* v2 = (const float2*)vslab;
    #pragma unroll 8
    for (int rr = 0; rr < 64; ++rr) {
        float2 a = u2[rr * 256 + tid];
        float2 b = v2[rr * 256 + tid];
        su.x += a.x; su.y += a.y;
        sv.x += b.x; sv.y += b.y;
    }
    float uu = su.x * su.x + su.y * su.y;
    float us = su.x + su.y;
    float uv = su.x * sv.x + su.y * sv.y;
    float tt = scalT[tid] + scalT[tid + 256];
    float pp = scalP[tid] + scalP[tid + 256];
    float qq = scalQ[tid] + scalQ[tid + 256];
    float wc = (tid < 64) ? scalW[tid] : 0.f;

    for (int off = 32; off > 0; off >>= 1) {
        uu += __shfl_down(uu, off);
        us += __shfl_down(us, off);
        uv += __shfl_down(uv, off);
        tt += __shfl_down(tt, off);
        pp += __shfl_down(pp, off);
        qq += __shfl_down(qq, off);
        wc += __shfl_down(wc, off);
    }
    __shared__ float red[7][4];
    if (lane == 0) {
        red[0][wave] = uu; red[1][wave] = us; red[2][wave] = uv;
        red[3][wave] = tt; red[4][wave] = pp; red[5][wave] = qq;
        red[6][wave] = wc;
    }
    __syncthreads();
    if (tid == 0) {
        double UU = 0, US = 0, UV = 0, T = 0, P = 0, Q = 0, WC = 0;
        for (int w = 0; w < 4; ++w) {
            UU += red[0][w]; US += red[1][w]; UV += red[2][w];
            T  += red[3][w]; P  += red[4][w]; Q  += red[5][w];
            WC += red[6][w];
        }
        const double N = (double)n, Dd = (double)d, eps = 1e-6;
        double Ssum = 2.0 * N * T - 2.0 * UU + N * N * Dd * eps * eps;
        double Anum = N * P + T * WC - 2.0 * UV
                    + 2.0 * eps * (N * Q - US * WC) + N * Dd * eps * eps * WC;
        double a = Anum / (N * WC);
        double b = (N * Ssum - Anum) / (N * (N * N - WC));
        out[0] = (float)(-a / b - b / a);
    }
}

extern "C" void kernel_launch(void* const* d_in, const int* in_sizes, int n_in,
                              void* d_out, int out_size, void* d_ws, size_t ws_size,
                              hipStream_t stream) {
    const float* x   = (const float*)d_in[0];
    const int*   tgt = (const int*)d_in[1];
    float*       out = (float*)d_out;

    const int n = in_sizes[1];          // 8192
    const int d = in_sizes[0] / n;      // 512

    char*         ws     = (char*)d_ws;
    float*        uslab  = (float*)ws;                 // 128 KB
    float*        vslab  = (float*)(ws + 131072);      // 128 KB
    float*        scalT  = (float*)(ws + 262144);      // 2 KB
    float*        scalP  = (float*)(ws + 264192);      // 2 KB
    float*        scalQ  = (float*)(ws + 266240);      // 2 KB
    float*        scalW  = (float*)(ws + 268288);      // 256 B
    unsigned int* ticket = (unsigned int*)(ws + 268544); // 4 B, poison-init 0xAAAAAAAA

    fused<<<512, 256, 0, stream>>>(x, tgt, uslab, vslab, scalT, scalP, scalQ,
                                   scalW, ticket, n, d, out);
}

// Round 10
// 77.445 us; speedup vs baseline: 1.0440x; 1.0440x over previous
//
#include <hip/hip_runtime.h>

#define NBINS 128

// Fixed problem shape: n = 8192 rows, d = 512 cols.
// Grid: 512 blocks = (cg in [0,8)) x (rg in [0,64)); bid = rg*8 + cg.
// Block (cg,rg) owns rows [rg*128, rg*128+128) x cols [cg*64, cg*64+64).
//
// Single-dispatch design. Cross-block handoff (~0.5 MB of partials) is done
// with agent-scope RELAXED atomic stores (write-through to device-coherent
// point, no L2 writeback), ordered by a wave-0 `s_waitcnt vmcnt(0)` before a
// RELAXED agent ticket fetch_add. The last block does one agent ACQUIRE fence
// (L2 invalidate only) and reads everything with plain vector loads.
//
// ws layout (bytes):
//   [0,      131072)  float uslab[64][512]
//   [131072, 262144)  float vslab[64][512]
//   [262144, 264192)  float scalT[512]
//   [264192, 266240)  float scalP[512]
//   [266240, 268288)  float scalQ[512]
//   [268288, 268544)  float scalW[64]
//   [268544, 268548)  uint  ticket   (harness poison 0xAAAAAAAA is the known init)

__global__ __launch_bounds__(256) void fused(const float* __restrict__ x,
                                             const int* __restrict__ tgt,
                                             float* __restrict__ uslab,
                                             float* __restrict__ vslab,
                                             float* __restrict__ scalT,
                                             float* __restrict__ scalP,
                                             float* __restrict__ scalQ,
                                             float* __restrict__ scalW,
                                             unsigned int* __restrict__ ticket,
                                             int n, int d,
                                             float* __restrict__ out) {
    const int tid  = threadIdx.x;
    const int bid  = blockIdx.x;
    const int cg   = bid & 7;     // column group (64 cols)
    const int rg   = bid >> 3;    // row group (128 rows)
    const int wave = tid >> 6, lane = tid & 63;

    __shared__ float xbuf[128 * 64];   // 32 KB tile
    __shared__ int   hw[4][NBINS];     // wave-private histograms
    __shared__ float crow[128];        // class counts for the block's rows
    __shared__ float ured[256 * 4];    // per-thread float4 u partials
    __shared__ float vred[256 * 4];
    __shared__ float redS[3][4];
    __shared__ unsigned int lastflag;

    // ---- (1) stage the 32 KB tile: 8 async 16B direct-to-LDS copies/thread ----
    const float* xb = x + (size_t)(rg * 128) * 512 + cg * 64;
    #pragma unroll
    for (int k = 0; k < 8; ++k) {
        const int e16   = (k * 4 + wave) * 64 + lane;
        const int row   = e16 >> 4;
        const int chunk = e16 & 15;
        const float* gptr = xb + (size_t)row * 512 + chunk * 4;
        float* lbase = &xbuf[(k * 4 + wave) * 256];   // wave-uniform; lane at +lane*16B
        __builtin_amdgcn_global_load_lds(
            (const __attribute__((address_space(1))) void*)gptr,
            (__attribute__((address_space(3))) void*)lbase, 16, 0, 0);
    }

    // ---- (2) targets: 8 int4/thread (all 8192), in flight with the staging ----
    int4 tv[8];
    const int4* t4 = (const int4*)tgt;
    #pragma unroll
    for (int k = 0; k < 8; ++k) tv[k] = t4[k * 256 + tid];

    const int mylab = (tid < 128) ? tgt[rg * 128 + tid] : 0;

    // ---- (3) wave-private LDS histogram ----
    hw[wave][lane] = 0;
    hw[wave][lane + 64] = 0;
    #pragma unroll
    for (int k = 0; k < 8; ++k) {
        atomicAdd(&hw[wave][tv[k].x & (NBINS - 1)], 1);
        atomicAdd(&hw[wave][tv[k].y & (NBINS - 1)], 1);
        atomicAdd(&hw[wave][tv[k].z & (NBINS - 1)], 1);
        atomicAdd(&hw[wave][tv[k].w & (NBINS - 1)], 1);
    }
    __syncthreads();   // drains staging vmcnt + all hist atomics

    if (tid < 128) {
        const int b = mylab & (NBINS - 1);
        crow[tid] = (float)(hw[0][b] + hw[1][b] + hw[2][b] + hw[3][b]);
    }
    __syncthreads();

    // ---- (4) accumulate: thread t -> col-quad q = t&15, rows g+16k, g = t>>4 ----
    const int q = tid & 15, g = tid >> 4;
    float t_acc = 0.f, p_acc = 0.f, q_acc = 0.f;
    float4 ua = make_float4(0.f, 0.f, 0.f, 0.f);
    float4 va = make_float4(0.f, 0.f, 0.f, 0.f);
    #pragma unroll
    for (int k = 0; k < 8; ++k) {
        const int r = g + 16 * k;
        const float c = crow[r];
        const float4 v = ((const float4*)xbuf)[r * 16 + q];
        const float sq = v.x*v.x + v.y*v.y + v.z*v.z + v.w*v.w;
        const float sm = v.x + v.y + v.z + v.w;
        t_acc += sq;
        p_acc += c * sq;
        q_acc += c * sm;
        ua.x += v.x;     ua.y += v.y;     ua.z += v.z;     ua.w += v.w;
        va.x += c * v.x; va.y += c * v.y; va.z += c * v.z; va.w += c * v.w;
    }

    ((float4*)ured)[tid] = ua;
    ((float4*)vred)[tid] = va;

    for (int off = 32; off > 0; off >>= 1) {
        t_acc += __shfl_down(t_acc, off);
        p_acc += __shfl_down(p_acc, off);
        q_acc += __shfl_down(q_acc, off);
    }
    if (lane == 0) { redS[0][wave] = t_acc; redS[1][wave] = p_acc; redS[2][wave] = q_acc; }
    __syncthreads();   // covers ured/vred, redS (crow already visible)

    // ---- (5) wave 0 ONLY: all cross-sync stores (agent-scope, write-through) ----
    if (wave == 0) {
        // column reduction: lane owns (cq = lane>>2, ce = lane&3)
        const int cq = lane >> 2, ce = lane & 3;
        float su = 0.f, sv = 0.f;
        #pragma unroll
        for (int gg = 0; gg < 16; ++gg) {
            su += ured[(gg * 16 + cq) * 4 + ce];
            sv += vred[(gg * 16 + cq) * 4 + ce];
        }
        __hip_atomic_store(&uslab[rg * 512 + cg * 64 + lane], su,
                           __ATOMIC_RELAXED, __HIP_MEMORY_SCOPE_AGENT);
        __hip_atomic_store(&vslab[rg * 512 + cg * 64 + lane], sv,
                           __ATOMIC_RELAXED, __HIP_MEMORY_SCOPE_AGENT);

        // Wsum over the block's 128 rows (wave-0 shuffle)
        float w = crow[lane] + crow[lane + 64];
        for (int off = 32; off > 0; off >>= 1) w += __shfl_down(w, off);

        if (lane == 0) {
            if (cg == 0)
                __hip_atomic_store(&scalW[rg], w,
                                   __ATOMIC_RELAXED, __HIP_MEMORY_SCOPE_AGENT);
            __hip_atomic_store(&scalT[bid], redS[0][0] + redS[0][1] + redS[0][2] + redS[0][3],
                               __ATOMIC_RELAXED, __HIP_MEMORY_SCOPE_AGENT);
            __hip_atomic_store(&scalP[bid], redS[1][0] + redS[1][1] + redS[1][2] + redS[1][3],
                               __ATOMIC_RELAXED, __HIP_MEMORY_SCOPE_AGENT);
            __hip_atomic_store(&scalQ[bid], redS[2][0] + redS[2][1] + redS[2][2] + redS[2][3],
                               __ATOMIC_RELAXED, __HIP_MEMORY_SCOPE_AGENT);

            // order: all wave-0 stores globally visible, THEN bump the ticket.
            asm volatile("s_waitcnt vmcnt(0)" ::: "memory");
            unsigned int old = __hip_atomic_fetch_add(ticket, 1u, __ATOMIC_RELAXED,
                                                      __HIP_MEMORY_SCOPE_AGENT);
            lastflag = (old == 0xAAAAAAAAu + 511u) || (old == 511u);
        }
    }
    __syncthreads();
    if (!lastflag) return;

    // ---- (6) winner: acquire (L2/L1 invalidate, no writeback), then finalize ----
    __builtin_amdgcn_fence(__ATOMIC_ACQUIRE, "agent");

    float2 su = make_float2(0.f, 0.f), sv = make_float2(0.f, 0.f);
    const float2* u2 = (const float2*)uslab;
    const float2* v2 = (const float2*)vslab;
    #pragma unroll 8
    for (int rr = 0; rr < 64; ++rr) {
        float2 a = u2[rr * 256 + tid];
        float2 b = v2[rr * 256 + tid];
        su.x += a.x; su.y += a.y;
        sv.x += b.x; sv.y += b.y;
    }
    float uu = su.x * su.x + su.y * su.y;
    float us = su.x + su.y;
    float uv = su.x * sv.x + su.y * sv.y;
    float tt = scalT[tid] + scalT[tid + 256];
    float pp = scalP[tid] + scalP[tid + 256];
    float qq = scalQ[tid] + scalQ[tid + 256];
    float wc = (tid < 64) ? scalW[tid] : 0.f;

    for (int off = 32; off > 0; off >>= 1) {
        uu += __shfl_down(uu, off);
        us += __shfl_down(us, off);
        uv += __shfl_down(uv, off);
        tt += __shfl_down(tt, off);
        pp += __shfl_down(pp, off);
        qq += __shfl_down(qq, off);
        wc += __shfl_down(wc, off);
    }
    __shared__ float red[7][4];
    if (lane == 0) {
        red[0][wave] = uu; red[1][wave] = us; red[2][wave] = uv;
        red[3][wave] = tt; red[4][wave] = pp; red[5][wave] = qq;
        red[6][wave] = wc;
    }
    __syncthreads();
    if (tid == 0) {
        double UU = 0, US = 0, UV = 0, T = 0, P = 0, Q = 0, WC = 0;
        for (int w = 0; w < 4; ++w) {
            UU += red[0][w]; US += red[1][w]; UV += red[2][w];
            T  += red[3][w]; P  += red[4][w]; Q  += red[5][w];
            WC += red[6][w];
        }
        const double N = (double)n, Dd = (double)d, eps = 1e-6;
        double Ssum = 2.0 * N * T - 2.0 * UU + N * N * Dd * eps * eps;
        double Anum = N * P + T * WC - 2.0 * UV
                    + 2.0 * eps * (N * Q - US * WC) + N * Dd * eps * eps * WC;
        double a = Anum / (N * WC);
        double b = (N * Ssum - Anum) / (N * (N * N - WC));
        out[0] = (float)(-a / b - b / a);
    }
}

extern "C" void kernel_launch(void* const* d_in, const int* in_sizes, int n_in,
                              void* d_out, int out_size, void* d_ws, size_t ws_size,
                              hipStream_t stream) {
    const float* x   = (const float*)d_in[0];
    const int*   tgt = (const int*)d_in[1];
    float*       out = (float*)d_out;

    const int n = in_sizes[1];          // 8192
    const int d = in_sizes[0] / n;      // 512

    char*         ws     = (char*)d_ws;
    float*        uslab  = (float*)ws;                 // 128 KB
    float*        vslab  = (float*)(ws + 131072);      // 128 KB
    float*        scalT  = (float*)(ws + 262144);      // 2 KB
    float*        scalP  = (float*)(ws + 264192);      // 2 KB
    float*        scalQ  = (float*)(ws + 266240);      // 2 KB
    float*        scalW  = (float*)(ws + 268288);      // 256 B
    unsigned int* ticket = (unsigned int*)(ws + 268544); // 4 B, poison-init 0xAAAAAAAA

    fused<<<512, 256, 0, stream>>>(x, tgt, uslab, vslab, scalT, scalP, scalQ,
                                   scalW, ticket, n, d, out);
}

// Round 11
// 75.382 us; speedup vs baseline: 1.0726x; 1.0274x over previous
//
#include <hip/hip_runtime.h>

#define NBINS 128

// Fixed problem shape: n = 8192 rows, d = 512 cols.
// Grid: 512 blocks = (cg in [0,8)) x (rg in [0,64)); bid = rg*8 + cg.
// Block (cg,rg) owns rows [rg*128, rg*128+128) x cols [cg*64, cg*64+64).
//
// Single dispatch. Cross-block handoff (~0.5 MB of partials) via agent-scope
// RELAXED atomic stores (write-through, no L2 writeback), ordered by a wave-0
// `s_waitcnt vmcnt(0)` before a RELAXED leaf-ticket fetch_add. Tickets form a
// 3-level tree (64 leaves / 8 mids / 1 root, 128B-spaced lines) so no line
// ever sees more than 8 RMWs — kills the R10 same-address serialization tail.
// The root winner does one agent ACQUIRE fence (invalidate only) and reads
// everything with plain vector loads.
//
// ws layout (bytes):
//   [0,      131072)  float uslab[64][512]
//   [131072, 262144)  float vslab[64][512]
//   [262144, 264192)  float scalT[512]
//   [264192, 266240)  float scalP[512]
//   [266240, 268288)  float scalQ[512]
//   [268288, 268544)  float scalW[64]
//   [268544, 277888)  uint  tickets[73*32]  (leaf rg at +rg*128B, mid m at
//                     +8192+m*128B, root at +9216B; poison 0xAAAAAAAA is the
//                     known init — winner checks old==POISON+7 || old==7)

__device__ __forceinline__ bool is_eighth(unsigned int old) {
    return (old == 0xAAAAAAAAu + 7u) || (old == 7u);
}

__global__ __launch_bounds__(256) void fused(const float* __restrict__ x,
                                             const int* __restrict__ tgt,
                                             float* __restrict__ uslab,
                                             float* __restrict__ vslab,
                                             float* __restrict__ scalT,
                                             float* __restrict__ scalP,
                                             float* __restrict__ scalQ,
                                             float* __restrict__ scalW,
                                             unsigned int* __restrict__ tickets,
                                             int n, int d,
                                             float* __restrict__ out) {
    const int tid  = threadIdx.x;
    const int bid  = blockIdx.x;
    const int cg   = bid & 7;     // column group (64 cols)
    const int rg   = bid >> 3;    // row group (128 rows)
    const int wave = tid >> 6, lane = tid & 63;

    __shared__ float xbuf[128 * 64];   // 32 KB tile
    __shared__ int   hw[4][NBINS];     // wave-private histograms
    __shared__ float crow[128];        // class counts for the block's rows
    __shared__ float ured[256 * 4];    // per-thread float4 u partials
    __shared__ float vred[256 * 4];
    __shared__ float redS[3][4];
    __shared__ unsigned int lastflag;

    // ---- (1) stage the 32 KB tile: 8 async 16B direct-to-LDS copies/thread ----
    const float* xb = x + (size_t)(rg * 128) * 512 + cg * 64;
    #pragma unroll
    for (int k = 0; k < 8; ++k) {
        const int e16   = (k * 4 + wave) * 64 + lane;
        const int row   = e16 >> 4;
        const int chunk = e16 & 15;
        const float* gptr = xb + (size_t)row * 512 + chunk * 4;
        float* lbase = &xbuf[(k * 4 + wave) * 256];   // wave-uniform; lane at +lane*16B
        __builtin_amdgcn_global_load_lds(
            (const __attribute__((address_space(1))) void*)gptr,
            (__attribute__((address_space(3))) void*)lbase, 16, 0, 0);
    }

    // ---- (2) targets: 8 int4/thread (all 8192), in flight with the staging ----
    int4 tv[8];
    const int4* t4 = (const int4*)tgt;
    #pragma unroll
    for (int k = 0; k < 8; ++k) tv[k] = t4[k * 256 + tid];

    const int mylab = (tid < 128) ? tgt[rg * 128 + tid] : 0;

    // ---- (3) wave-private LDS histogram ----
    hw[wave][lane] = 0;
    hw[wave][lane + 64] = 0;
    #pragma unroll
    for (int k = 0; k < 8; ++k) {
        atomicAdd(&hw[wave][tv[k].x & (NBINS - 1)], 1);
        atomicAdd(&hw[wave][tv[k].y & (NBINS - 1)], 1);
        atomicAdd(&hw[wave][tv[k].z & (NBINS - 1)], 1);
        atomicAdd(&hw[wave][tv[k].w & (NBINS - 1)], 1);
    }
    __syncthreads();   // drains staging vmcnt + all hist atomics

    if (tid < 128) {
        const int b = mylab & (NBINS - 1);
        crow[tid] = (float)(hw[0][b] + hw[1][b] + hw[2][b] + hw[3][b]);
    }
    __syncthreads();

    // ---- (4) accumulate: thread t -> col-quad q = t&15, rows g+16k, g = t>>4 ----
    const int q = tid & 15, g = tid >> 4;
    float t_acc = 0.f, p_acc = 0.f, q_acc = 0.f;
    float4 ua = make_float4(0.f, 0.f, 0.f, 0.f);
    float4 va = make_float4(0.f, 0.f, 0.f, 0.f);
    #pragma unroll
    for (int k = 0; k < 8; ++k) {
        const int r = g + 16 * k;
        const float c = crow[r];
        const float4 v = ((const float4*)xbuf)[r * 16 + q];
        const float sq = v.x*v.x + v.y*v.y + v.z*v.z + v.w*v.w;
        const float sm = v.x + v.y + v.z + v.w;
        t_acc += sq;
        p_acc += c * sq;
        q_acc += c * sm;
        ua.x += v.x;     ua.y += v.y;     ua.z += v.z;     ua.w += v.w;
        va.x += c * v.x; va.y += c * v.y; va.z += c * v.z; va.w += c * v.w;
    }

    ((float4*)ured)[tid] = ua;
    ((float4*)vred)[tid] = va;

    for (int off = 32; off > 0; off >>= 1) {
        t_acc += __shfl_down(t_acc, off);
        p_acc += __shfl_down(p_acc, off);
        q_acc += __shfl_down(q_acc, off);
    }
    if (lane == 0) { redS[0][wave] = t_acc; redS[1][wave] = p_acc; redS[2][wave] = q_acc; }
    __syncthreads();   // covers ured/vred, redS

    // ---- (5) wave 0 ONLY: all cross-sync stores (agent-scope, write-through) ----
    if (wave == 0) {
        const int cq = lane >> 2, ce = lane & 3;
        float su = 0.f, sv = 0.f;
        #pragma unroll
        for (int gg = 0; gg < 16; ++gg) {
            su += ured[(gg * 16 + cq) * 4 + ce];
            sv += vred[(gg * 16 + cq) * 4 + ce];
        }
        __hip_atomic_store(&uslab[rg * 512 + cg * 64 + lane], su,
                           __ATOMIC_RELAXED, __HIP_MEMORY_SCOPE_AGENT);
        __hip_atomic_store(&vslab[rg * 512 + cg * 64 + lane], sv,
                           __ATOMIC_RELAXED, __HIP_MEMORY_SCOPE_AGENT);

        float w = crow[lane] + crow[lane + 64];
        for (int off = 32; off > 0; off >>= 1) w += __shfl_down(w, off);

        if (lane == 0) {
            if (cg == 0)
                __hip_atomic_store(&scalW[rg], w,
                                   __ATOMIC_RELAXED, __HIP_MEMORY_SCOPE_AGENT);
            __hip_atomic_store(&scalT[bid], redS[0][0] + redS[0][1] + redS[0][2] + redS[0][3],
                               __ATOMIC_RELAXED, __HIP_MEMORY_SCOPE_AGENT);
            __hip_atomic_store(&scalP[bid], redS[1][0] + redS[1][1] + redS[1][2] + redS[1][3],
                               __ATOMIC_RELAXED, __HIP_MEMORY_SCOPE_AGENT);
            __hip_atomic_store(&scalQ[bid], redS[2][0] + redS[2][1] + redS[2][2] + redS[2][3],
                               __ATOMIC_RELAXED, __HIP_MEMORY_SCOPE_AGENT);

            // all wave-0 stores globally visible, THEN climb the ticket tree.
            asm volatile("s_waitcnt vmcnt(0)" ::: "memory");
            unsigned int f = 0;
            unsigned int* leaf = tickets + rg * 32;            // 64 lines, 8 bumps each
            unsigned int o1 = __hip_atomic_fetch_add(leaf, 1u, __ATOMIC_RELAXED,
                                                     __HIP_MEMORY_SCOPE_AGENT);
            if (is_eighth(o1)) {
                unsigned int* mid = tickets + 64 * 32 + (rg >> 3) * 32;  // 8 lines
                unsigned int o2 = __hip_atomic_fetch_add(mid, 1u, __ATOMIC_RELAXED,
                                                         __HIP_MEMORY_SCOPE_AGENT);
                if (is_eighth(o2)) {
                    unsigned int* root = tickets + 72 * 32;              // 8 bumps
                    unsigned int o3 = __hip_atomic_fetch_add(root, 1u, __ATOMIC_RELAXED,
                                                             __HIP_MEMORY_SCOPE_AGENT);
                    f = is_eighth(o3) ? 1u : 0u;
                }
            }
            lastflag = f;
        }
    }
    __syncthreads();
    if (!lastflag) return;

    // ---- (6) root winner: acquire (invalidate only), then finalize ----
    __builtin_amdgcn_fence(__ATOMIC_ACQUIRE, "agent");

    float2 su = make_float2(0.f, 0.f), sv = make_float2(0.f, 0.f);
    const float2* u2 = (const float2*)uslab;
    const float2* v2 = (const float2*)vslab;
    #pragma unroll 8
    for (int rr = 0; rr < 64; ++rr) {
        float2 a = u2[rr * 256 + tid];
        float2 b = v2[rr * 256 + tid];
        su.x += a.x; su.y += a.y;
        sv.x += b.x; sv.y += b.y;
    }
    float uu = su.x * su.x + su.y * su.y;
    float us = su.x + su.y;
    float uv = su.x * sv.x + su.y * sv.y;
    float tt = scalT[tid] + scalT[tid + 256];
    float pp = scalP[tid] + scalP[tid + 256];
    float qq = scalQ[tid] + scalQ[tid + 256];
    float wc = (tid < 64) ? scalW[tid] : 0.f;

    for (int off = 32; off > 0; off >>= 1) {
        uu += __shfl_down(uu, off);
        us += __shfl_down(us, off);
        uv += __shfl_down(uv, off);
        tt += __shfl_down(tt, off);
        pp += __shfl_down(pp, off);
        qq += __shfl_down(qq, off);
        wc += __shfl_down(wc, off);
    }
    __shared__ float red[7][4];
    if (lane == 0) {
        red[0][wave] = uu; red[1][wave] = us; red[2][wave] = uv;
        red[3][wave] = tt; red[4][wave] = pp; red[5][wave] = qq;
        red[6][wave] = wc;
    }
    __syncthreads();
    if (tid == 0) {
        double UU = 0, US = 0, UV = 0, T = 0, P = 0, Q = 0, WC = 0;
        for (int w = 0; w < 4; ++w) {
            UU += red[0][w]; US += red[1][w]; UV += red[2][w];
            T  += red[3][w]; P  += red[4][w]; Q  += red[5][w];
            WC += red[6][w];
        }
        const double N = (double)n, Dd = (double)d, eps = 1e-6;
        double Ssum = 2.0 * N * T - 2.0 * UU + N * N * Dd * eps * eps;
        double Anum = N * P + T * WC - 2.0 * UV
                    + 2.0 * eps * (N * Q - US * WC) + N * Dd * eps * eps * WC;
        double a = Anum / (N * WC);
        double b = (N * Ssum - Anum) / (N * (N * N - WC));
        out[0] = (float)(-a / b - b / a);
    }
}

extern "C" void kernel_launch(void* const* d_in, const int* in_sizes, int n_in,
                              void* d_out, int out_size, void* d_ws, size_t ws_size,
                              hipStream_t stream) {
    const float* x   = (const float*)d_in[0];
    const int*   tgt = (const int*)d_in[1];
    float*       out = (float*)d_out;

    const int n = in_sizes[1];          // 8192
    const int d = in_sizes[0] / n;      // 512

    char*         ws      = (char*)d_ws;
    float*        uslab   = (float*)ws;                 // 128 KB
    float*        vslab   = (float*)(ws + 131072);      // 128 KB
    float*        scalT   = (float*)(ws + 262144);      // 2 KB
    float*        scalP   = (float*)(ws + 264192);      // 2 KB
    float*        scalQ   = (float*)(ws + 266240);      // 2 KB
    float*        scalW   = (float*)(ws + 268288);      // 256 B
    unsigned int* tickets = (unsigned int*)(ws + 268544); // 73*128 B, poison-init

    fused<<<512, 256, 0, stream>>>(x, tgt, uslab, vslab, scalT, scalP, scalQ,
                                   scalW, tickets, n, d, out);
}

// Round 12
// 70.735 us; speedup vs baseline: 1.1431x; 1.0657x over previous
//
#include <hip/hip_runtime.h>

#define NBINS 128

// Fixed problem shape: n = 8192 rows, d = 512 cols.
// Grid: 512 blocks = (cg in [0,8)) x (rg in [0,64)); bid = rg*8 + cg.
// Block (cg,rg) owns rows [rg*128, rg*128+128) x cols [cg*64, cg*64+64).
//
// Two dispatches (proven optimum across R2..R11):
//   main_pass: plain disjoint stores, no atomics, no fences, no init needed.
//   finalk:    1 block; dispatch boundary provides cross-XCD coherence.
//
// ws layout (bytes) — every byte finalk reads is plain-stored exactly once:
//   [0,      131072)  float uslab[64][512]
//   [131072, 262144)  float vslab[64][512]
//   [262144, 264192)  float scalT[512]
//   [264192, 266240)  float scalP[512]
//   [266240, 268288)  float scalQ[512]
//   [268288, 268544)  float scalW[64]

__global__ __launch_bounds__(256) void main_pass(const float* __restrict__ x,
                                                 const int* __restrict__ tgt,
                                                 float* __restrict__ uslab,
                                                 float* __restrict__ vslab,
                                                 float* __restrict__ scalT,
                                                 float* __restrict__ scalP,
                                                 float* __restrict__ scalQ,
                                                 float* __restrict__ scalW) {
    const int tid  = threadIdx.x;
    const int bid  = blockIdx.x;
    const int cg   = bid & 7;     // column group (64 cols)
    const int rg   = bid >> 3;    // row group (128 rows)
    const int wave = tid >> 6, lane = tid & 63;

    __shared__ float xbuf[128 * 64];   // 32 KB tile
    __shared__ int   hw[4][NBINS];     // wave-private histograms
    __shared__ float crow[128];        // class counts for the block's rows
    __shared__ float ured[256 * 4];    // per-thread float4 u partials
    __shared__ float vred[256 * 4];
    __shared__ float redS[3][4];

    // ---- (1) stage the 32 KB tile: 8 async 16B direct-to-LDS copies/thread ----
    const float* xb = x + (size_t)(rg * 128) * 512 + cg * 64;
    #pragma unroll
    for (int k = 0; k < 8; ++k) {
        const int e16   = (k * 4 + wave) * 64 + lane;
        const int row   = e16 >> 4;
        const int chunk = e16 & 15;
        const float* gptr = xb + (size_t)row * 512 + chunk * 4;
        float* lbase = &xbuf[(k * 4 + wave) * 256];   // wave-uniform; lane at +lane*16B
        __builtin_amdgcn_global_load_lds(
            (const __attribute__((address_space(1))) void*)gptr,
            (__attribute__((address_space(3))) void*)lbase, 16, 0, 0);
    }

    // ---- (2) targets: 8 int4/thread (all 8192), in flight with the staging ----
    int4 tv[8];
    const int4* t4 = (const int4*)tgt;
    #pragma unroll
    for (int k = 0; k < 8; ++k) tv[k] = t4[k * 256 + tid];

    const int mylab = (tid < 128) ? tgt[rg * 128 + tid] : 0;

    // ---- (3) wave-private LDS histogram ----
    hw[wave][lane] = 0;
    hw[wave][lane + 64] = 0;
    #pragma unroll
    for (int k = 0; k < 8; ++k) {
        atomicAdd(&hw[wave][tv[k].x & (NBINS - 1)], 1);
        atomicAdd(&hw[wave][tv[k].y & (NBINS - 1)], 1);
        atomicAdd(&hw[wave][tv[k].z & (NBINS - 1)], 1);
        atomicAdd(&hw[wave][tv[k].w & (NBINS - 1)], 1);
    }
    __syncthreads();   // drains staging vmcnt + all hist atomics

    if (tid < 128) {
        const int b = mylab & (NBINS - 1);
        crow[tid] = (float)(hw[0][b] + hw[1][b] + hw[2][b] + hw[3][b]);
    }
    __syncthreads();

    // ---- (4) accumulate: thread t -> col-quad q = t&15, rows g+16k, g = t>>4 ----
    const int q = tid & 15, g = tid >> 4;
    float t_acc = 0.f, p_acc = 0.f, q_acc = 0.f;
    float4 ua = make_float4(0.f, 0.f, 0.f, 0.f);
    float4 va = make_float4(0.f, 0.f, 0.f, 0.f);
    #pragma unroll
    for (int k = 0; k < 8; ++k) {
        const int r = g + 16 * k;
        const float c = crow[r];
        const float4 v = ((const float4*)xbuf)[r * 16 + q];
        const float sq = v.x*v.x + v.y*v.y + v.z*v.z + v.w*v.w;
        const float sm = v.x + v.y + v.z + v.w;
        t_acc += sq;
        p_acc += c * sq;
        q_acc += c * sm;
        ua.x += v.x;     ua.y += v.y;     ua.z += v.z;     ua.w += v.w;
        va.x += c * v.x; va.y += c * v.y; va.z += c * v.z; va.w += c * v.w;
    }

    ((float4*)ured)[tid] = ua;
    ((float4*)vred)[tid] = va;

    for (int off = 32; off > 0; off >>= 1) {
        t_acc += __shfl_down(t_acc, off);
        p_acc += __shfl_down(p_acc, off);
        q_acc += __shfl_down(q_acc, off);
    }
    if (lane == 0) { redS[0][wave] = t_acc; redS[1][wave] = p_acc; redS[2][wave] = q_acc; }
    __syncthreads();   // covers ured/vred and redS

    // ---- (5) column reduction + disjoint slab stores (no atomics) ----
    if (tid < 64) {
        const int cq = tid >> 2, ce = tid & 3;
        float su = 0.f, sv = 0.f;
        #pragma unroll
        for (int gg = 0; gg < 16; ++gg) {
            su += ured[(gg * 16 + cq) * 4 + ce];
            sv += vred[(gg * 16 + cq) * 4 + ce];
        }
        uslab[rg * 512 + cg * 64 + tid] = su;
        vslab[rg * 512 + cg * 64 + tid] = sv;
    }

    if (wave == 1) {
        float w = crow[lane] + crow[lane + 64];
        for (int off = 32; off > 0; off >>= 1) w += __shfl_down(w, off);
        if (lane == 0 && cg == 0) scalW[rg] = w;
    }

    if (tid == 0) {
        scalT[bid] = redS[0][0] + redS[0][1] + redS[0][2] + redS[0][3];
        scalP[bid] = redS[1][0] + redS[1][1] + redS[1][2] + redS[1][3];
        scalQ[bid] = redS[2][0] + redS[2][1] + redS[2][2] + redS[2][3];
    }
}

// ---------------- final: MLP-optimized slab reduce + closed form ----------------
__global__ __launch_bounds__(256) void finalk(const float* __restrict__ uslab,
                                              const float* __restrict__ vslab,
                                              const float* __restrict__ scalT,
                                              const float* __restrict__ scalP,
                                              const float* __restrict__ scalQ,
                                              const float* __restrict__ scalW,
                                              int n, int d,
                                              float* __restrict__ out) {
    const int tid  = threadIdx.x;
    const int wave = tid >> 6, lane = tid & 63;

    __shared__ float ush4[128 * 4];   // column sums of u (512 floats)
    __shared__ float vsh4[128 * 4];

    // Phase A: threads 0..127 reduce u columns, 128..255 reduce v columns.
    // Thread handles one float4 col-group: 64 fully independent float4 loads.
    {
        const int c4 = tid & 127;
        const float4* slab4 = (const float4*)((tid < 128) ? uslab : vslab);
        float4 acc = make_float4(0.f, 0.f, 0.f, 0.f);
        #pragma unroll 16
        for (int rg = 0; rg < 64; ++rg) {
            float4 a = slab4[rg * 128 + c4];
            acc.x += a.x; acc.y += a.y; acc.z += a.z; acc.w += a.w;
        }
        float* dst = (tid < 128) ? ush4 : vsh4;
        ((float4*)dst)[c4] = acc;
    }

    // scalar partial arrays (independent loads, overlap with Phase A)
    float tt = scalT[tid] + scalT[tid + 256];
    float pp = scalP[tid] + scalP[tid + 256];
    float qq = scalQ[tid] + scalQ[tid + 256];
    float wc = (tid < 64) ? scalW[tid] : 0.f;
    __syncthreads();

    // Phase B: threads 0..127 compute uu/us/uv over their 4 columns.
    float uu = 0.f, us = 0.f, uv = 0.f;
    if (tid < 128) {
        float4 u4 = ((const float4*)ush4)[tid];
        float4 v4 = ((const float4*)vsh4)[tid];
        uu = u4.x*u4.x + u4.y*u4.y + u4.z*u4.z + u4.w*u4.w;
        us = u4.x + u4.y + u4.z + u4.w;
        uv = u4.x*v4.x + u4.y*v4.y + u4.z*v4.z + u4.w*v4.w;
    }

    for (int off = 32; off > 0; off >>= 1) {
        uu += __shfl_down(uu, off);
        us += __shfl_down(us, off);
        uv += __shfl_down(uv, off);
        tt += __shfl_down(tt, off);
        pp += __shfl_down(pp, off);
        qq += __shfl_down(qq, off);
        wc += __shfl_down(wc, off);
    }
    __shared__ float red[7][4];
    if (lane == 0) {
        red[0][wave] = uu; red[1][wave] = us; red[2][wave] = uv;
        red[3][wave] = tt; red[4][wave] = pp; red[5][wave] = qq;
        red[6][wave] = wc;
    }
    __syncthreads();
    if (tid == 0) {
        double UU = 0, US = 0, UV = 0, T = 0, P = 0, Q = 0, WC = 0;
        for (int w = 0; w < 4; ++w) {
            UU += red[0][w]; US += red[1][w]; UV += red[2][w];
            T  += red[3][w]; P  += red[4][w]; Q  += red[5][w];
            WC += red[6][w];
        }
        const double N = (double)n, Dd = (double)d, eps = 1e-6;
        double Ssum = 2.0 * N * T - 2.0 * UU + N * N * Dd * eps * eps;
        double Anum = N * P + T * WC - 2.0 * UV
                    + 2.0 * eps * (N * Q - US * WC) + N * Dd * eps * eps * WC;
        double a = Anum / (N * WC);
        double b = (N * Ssum - Anum) / (N * (N * N - WC));
        out[0] = (float)(-a / b - b / a);
    }
}

extern "C" void kernel_launch(void* const* d_in, const int* in_sizes, int n_in,
                              void* d_out, int out_size, void* d_ws, size_t ws_size,
                              hipStream_t stream) {
    const float* x   = (const float*)d_in[0];
    const int*   tgt = (const int*)d_in[1];
    float*       out = (float*)d_out;

    const int n = in_sizes[1];          // 8192
    const int d = in_sizes[0] / n;      // 512

    char*  ws    = (char*)d_ws;
    float* uslab = (float*)ws;                       // 128 KB
    float* vslab = (float*)(ws + 131072);            // 128 KB
    float* scalT = (float*)(ws + 262144);            // 2 KB
    float* scalP = (float*)(ws + 264192);            // 2 KB
    float* scalQ = (float*)(ws + 266240);            // 2 KB
    float* scalW = (float*)(ws + 268288);            // 256 B

    main_pass<<<512, 256, 0, stream>>>(x, tgt, uslab, vslab, scalT, scalP, scalQ, scalW);
    finalk   <<<1,   256, 0, stream>>>(uslab, vslab, scalT, scalP, scalQ, scalW, n, d, out);
}